// Round 7
// baseline (295.306 us; speedup 1.0000x reference)
//
#include <hip/hip_runtime.h>
#include <math.h>

#define SEQ 576
#define DIM 192
#define INNER 384
#define NHEAD 96
#define HS 24
#define WSZ 24
#define GIN 1152
#define NB 256
#define BLK 384
#define UPA 68
#define UPB 36
#define GBK 288
#define GKS 4
#define WP 36
#define DNA 20
#define DNB 36

// sense-reversal grid barrier; cnt/gen live in d_ws (zeroed each call)
__device__ __forceinline__ void gbar(unsigned* cnt, unsigned* gen) {
  __syncthreads();
  if (threadIdx.x == 0) {
    __threadfence();
    unsigned g = __hip_atomic_load(gen, __ATOMIC_RELAXED, __HIP_MEMORY_SCOPE_AGENT);
    unsigned arrived = __hip_atomic_fetch_add(cnt, 1u, __ATOMIC_ACQ_REL, __HIP_MEMORY_SCOPE_AGENT);
    if (arrived == gridDim.x - 1) {
      __hip_atomic_store(cnt, 0u, __ATOMIC_RELAXED, __HIP_MEMORY_SCOPE_AGENT);
      __hip_atomic_fetch_add(gen, 1u, __ATOMIC_RELEASE, __HIP_MEMORY_SCOPE_AGENT);
    } else {
      while (__hip_atomic_load(gen, __ATOMIC_ACQUIRE, __HIP_MEMORY_SCOPE_AGENT) == g)
        __builtin_amdgcn_s_sleep(8);
    }
    __threadfence();
  }
  __syncthreads();
}

__global__ __launch_bounds__(BLK) void k_mega(
    const float* __restrict__ x,
    const float* __restrict__ lnw, const float* __restrict__ lnb,
    const float* __restrict__ upw, const float* __restrict__ upb,
    const float* __restrict__ qw, const float* __restrict__ qb,
    const float* __restrict__ kwb, const float* __restrict__ kb,
    const float* __restrict__ vw, const float* __restrict__ vb,
    const float* __restrict__ cw, const float* __restrict__ cb,
    const float* __restrict__ igw, const float* __restrict__ igb,
    const float* __restrict__ fgw, const float* __restrict__ fgb,
    const float* __restrict__ onw, const float* __restrict__ skip,
    const float* __restrict__ dw, const float* __restrict__ db,
    float* __restrict__ out,
    float* __restrict__ xinner, float* __restrict__ xa,
    float* __restrict__ ginT, float* __restrict__ pig,
    float* __restrict__ pfg, float* __restrict__ es_g,
    float* __restrict__ pm_g, float* __restrict__ mx_g,
    float* __restrict__ hbuf, unsigned* __restrict__ bar) {
  __shared__ float lds[28800];            // 115.2 KB -> 1 block/CU
  int bid = blockIdx.x, t = threadIdx.x;
  unsigned* cnt = bar; unsigned* gen = bar + 1;

  // ---------- P1: LayerNorm + up-proj GEMM (216 blocks: 9 m x 24 n) ----------
  if (bid < 216) {
    int m0 = (bid % 9) * 64, n0 = (bid / 9) * 32;
    float* As = lds;             // [192][68]
    float* Bs = lds + 13056;     // [192][36]
    float* mu = lds + 19968;     // [64]
    float* inv = lds + 20032;    // [64]
    float* ps = lds + 20096;     // [192]
    for (int idx = t; idx < 64 * 48; idx += BLK) {
      int r = idx / 48, k4 = idx % 48;
      float4 v = *(const float4*)&x[(m0 + r) * DIM + 4 * k4];
      As[(4 * k4 + 0) * UPA + r] = v.x;
      As[(4 * k4 + 1) * UPA + r] = v.y;
      As[(4 * k4 + 2) * UPA + r] = v.z;
      As[(4 * k4 + 3) * UPA + r] = v.w;
    }
    for (int idx = t; idx < 32 * 48; idx += BLK) {
      int r = idx / 48, k4 = idx % 48;
      float4 v = *(const float4*)&upw[(n0 + r) * DIM + 4 * k4];
      Bs[(4 * k4 + 0) * UPB + r] = v.x;
      Bs[(4 * k4 + 1) * UPB + r] = v.y;
      Bs[(4 * k4 + 2) * UPB + r] = v.z;
      Bs[(4 * k4 + 3) * UPB + r] = v.w;
    }
    __syncthreads();
    if (t < 192) {
      int r = t % 64, ph = t / 64;
      float s_ = 0.f;
      #pragma unroll 8
      for (int k = ph * 64; k < ph * 64 + 64; ++k) s_ += As[k * UPA + r];
      ps[t] = s_;
    }
    __syncthreads();
    if (t < 64) mu[t] = (ps[t] + ps[64 + t] + ps[128 + t]) * (1.0f / DIM);
    __syncthreads();
    if (t < 192) {
      int r = t % 64, ph = t / 64;
      float m_ = mu[r], s_ = 0.f;
      #pragma unroll 8
      for (int k = ph * 64; k < ph * 64 + 64; ++k) {
        float d = As[k * UPA + r] - m_; s_ += d * d;
      }
      ps[t] = s_;
    }
    __syncthreads();
    if (t < 64) inv[t] = rsqrtf((ps[t] + ps[64 + t] + ps[128 + t]) * (1.0f / DIM) + 1e-5f);
    __syncthreads();
    for (int idx = t; idx < 64 * DIM; idx += BLK) {
      int k = idx / 64, r = idx % 64;
      As[k * UPA + r] = (As[k * UPA + r] - mu[r]) * inv[r] * lnw[k] + lnb[k];
    }
    __syncthreads();
    if (t < 256) {
      int gm = t >> 4, gn = t & 15;
      float acc[4][2];
      #pragma unroll
      for (int i = 0; i < 4; ++i)
        #pragma unroll
        for (int j = 0; j < 2; ++j) acc[i][j] = upb[n0 + 2 * gn + j];
      #pragma unroll 4
      for (int kk = 0; kk < DIM; ++kk) {
        float4 a = *(const float4*)&As[kk * UPA + 4 * gm];
        float2 bv = *(const float2*)&Bs[kk * UPB + 2 * gn];
        acc[0][0] += a.x * bv.x; acc[0][1] += a.x * bv.y;
        acc[1][0] += a.y * bv.x; acc[1][1] += a.y * bv.y;
        acc[2][0] += a.z * bv.x; acc[2][1] += a.z * bv.y;
        acc[3][0] += a.w * bv.x; acc[3][1] += a.w * bv.y;
      }
      #pragma unroll
      for (int i = 0; i < 4; ++i)
        *(float2*)&xinner[(m0 + 4 * gm + i) * (2 * INNER) + n0 + 2 * gn] =
            make_float2(acc[i][0], acc[i][1]);
    }
  }
  gbar(cnt, gen);

  // ---------- P2: conv3x3 + SiLU + headwise qkv (grid-stride tokens) ----------
  {
    float* xat = lds;
    float* xmt = lds + 384;
    for (int s = bid; s < SEQ; s += NB) {
      int h = s / WSZ, wc = s % WSZ;
      float acc = cb[t];
      #pragma unroll
      for (int kh = 0; kh < 3; ++kh) {
        int hh2 = h + kh - 1;
        if (hh2 < 0 || hh2 >= HS) continue;
        #pragma unroll
        for (int kw2 = 0; kw2 < 3; ++kw2) {
          int ww = wc + kw2 - 1;
          if (ww < 0 || ww >= WSZ) continue;
          acc += xinner[(hh2 * WSZ + ww) * (2 * INNER) + t] * cw[t * 9 + kh * 3 + kw2];
        }
      }
      float sil = acc / (1.0f + __expf(-acc));
      float xm = xinner[s * (2 * INNER) + t];
      __syncthreads();
      xat[t] = sil;
      xa[s * INNER + t] = sil;
      xmt[t] = xm;
      __syncthreads();
      int n = t >> 2, o = t & 3;
      const float* xah = xat + n * 4;
      const float* xmh = xmt + n * 4;
      float q = qb[t], k = kb[t], v = vb[t];
      #pragma unroll
      for (int i = 0; i < 4; ++i) {
        q += xah[i] * qw[n * 16 + o * 4 + i];
        k += xah[i] * kwb[n * 16 + o * 4 + i];
        v += xmh[i] * vw[n * 16 + o * 4 + i];
      }
      ginT[t * SEQ + s]               = q;
      ginT[(INNER + t) * SEQ + s]     = k;
      ginT[(2 * INNER + t) * SEQ + s] = v;
    }
  }
  gbar(cnt, gen);

  // ---------- P3: gate GEMM, K-split 4 (216 blocks) ----------
  if (bid < 216) {
    int bx = bid % 6, s0 = ((bid / 6) % 9) * 64, ks = bid / 54;
    int k0 = ks * GBK;
    bool isig = bx < 3;
    int m0 = (isig ? bx : bx - 3) * 32;
    const float* wb = (isig ? igw : fgw) + m0 * GIN;
    float* Ws = lds;              // [288][36]
    float* Gs = lds + GBK * WP;   // [288][64]
    for (int idx = t; idx < 32 * 72; idx += BLK) {
      int r = idx / 72, k4 = idx % 72;
      float4 v = *(const float4*)&wb[r * GIN + k0 + 4 * k4];
      Ws[(4 * k4 + 0) * WP + r] = v.x;
      Ws[(4 * k4 + 1) * WP + r] = v.y;
      Ws[(4 * k4 + 2) * WP + r] = v.z;
      Ws[(4 * k4 + 3) * WP + r] = v.w;
    }
    for (int idx = t; idx < GBK * 16; idx += BLK) {
      int kk = idx / 16, s4 = idx % 16;
      *(float4*)&Gs[kk * 64 + 4 * s4] =
          *(const float4*)&ginT[(k0 + kk) * SEQ + s0 + 4 * s4];
    }
    __syncthreads();
    if (t < 256) {
      int gm = t >> 4, gn = t & 15;
      float acc[2][4] = {{0.f,0.f,0.f,0.f},{0.f,0.f,0.f,0.f}};
      #pragma unroll 4
      for (int kk = 0; kk < GBK; ++kk) {
        float2 wv = *(const float2*)&Ws[kk * WP + 2 * gm];
        float4 gv = *(const float4*)&Gs[kk * 64 + 4 * gn];
        acc[0][0] += wv.x * gv.x; acc[0][1] += wv.x * gv.y;
        acc[0][2] += wv.x * gv.z; acc[0][3] += wv.x * gv.w;
        acc[1][0] += wv.y * gv.x; acc[1][1] += wv.y * gv.y;
        acc[1][2] += wv.y * gv.z; acc[1][3] += wv.y * gv.w;
      }
      float* dstp = (isig ? pig : pfg) + ks * NHEAD * SEQ;
      #pragma unroll
      for (int i = 0; i < 2; ++i) {
        int mm = m0 + 2 * gm + i;
        *(float4*)&dstp[mm * SEQ + s0 + 4 * gn] =
            make_float4(acc[i][0], acc[i][1], acc[i][2], acc[i][3]);
      }
    }
  }
  gbar(cnt, gen);

  // ---------- P4: combine partials + log-sigmoid + cumsum/prefix-max ----------
  if (bid < NHEAD && t < 64) {
    int n = bid;
    float bi = igb[n], bf = fgb[n];
    float carryS = 0.f, carryM = -3.0e38f;
    const int H4 = NHEAD * SEQ;
    for (int c = 0; c < SEQ / 64; ++c) {
      int off = n * SEQ + c * 64 + t;
      float ai = bi + pig[off] + pig[off + H4] + pig[off + 2 * H4] + pig[off + 3 * H4];
      float af = bf + pfg[off] + pfg[off + H4] + pfg[off + 2 * H4] + pfg[off + 3 * H4];
      float lf = (af >= 0.f) ? -log1pf(expf(-af)) : (af - log1pf(expf(af)));
      float v = lf;
      #pragma unroll
      for (int o2 = 1; o2 < 64; o2 <<= 1) {
        float u = __shfl_up(v, o2);
        if (t >= o2) v += u;
      }
      v += carryS;
      carryS = __shfl(v, 63);
      float e = ai - v;
      es_g[off] = e;
      float m = e;
      #pragma unroll
      for (int o2 = 1; o2 < 64; o2 <<= 1) {
        float u = __shfl_up(m, o2);
        if (t >= o2) m = fmaxf(m, u);
      }
      m = fmaxf(m, carryM);
      carryM = __shfl(m, 63);
      pm_g[off] = m;
      mx_g[off] = v + m;
    }
  }
  gbar(cnt, gen);

  // ---------- P5: mLSTM triangular accumulate + groupnorm (96 x 2) ----------
  if (bid < 2 * NHEAD) {
    int n = bid % NHEAD, hh = bid / NHEAD;
    int cnt2 = 288 * (hh + 1);
    float* ksm = lds;               // [576][4]
    float* vsm = lds + 2304;        // [576][4]
    float* esm = lds + 4608;        // [576]
    for (int tt = t; tt < cnt2; tt += BLK) {
      float a0 = ginT[(INNER + n * 4 + 0) * SEQ + tt] * 0.5f;
      float a1 = ginT[(INNER + n * 4 + 1) * SEQ + tt] * 0.5f;
      float a2 = ginT[(INNER + n * 4 + 2) * SEQ + tt] * 0.5f;
      float a3 = ginT[(INNER + n * 4 + 3) * SEQ + tt] * 0.5f;
      *(float4*)&ksm[tt * 4] = make_float4(a0, a1, a2, a3);
      float b0 = ginT[(2 * INNER + n * 4 + 0) * SEQ + tt];
      float b1 = ginT[(2 * INNER + n * 4 + 1) * SEQ + tt];
      float b2 = ginT[(2 * INNER + n * 4 + 2) * SEQ + tt];
      float b3 = ginT[(2 * INNER + n * 4 + 3) * SEQ + tt];
      *(float4*)&vsm[tt * 4] = make_float4(b0, b1, b2, b3);
      esm[tt] = es_g[n * SEQ + tt];
    }
    __syncthreads();
    if (t < 288) {
      int s = 288 * hh + t;
      float q0 = ginT[(n * 4 + 0) * SEQ + s];
      float q1 = ginT[(n * 4 + 1) * SEQ + s];
      float q2 = ginT[(n * 4 + 2) * SEQ + s];
      float q3 = ginT[(n * 4 + 3) * SEQ + s];
      float pm = pm_g[n * SEQ + s];
      float mx = mx_g[n * SEQ + s];
      float csum = 0.f, h0 = 0.f, h1 = 0.f, h2 = 0.f, h3 = 0.f;
      for (int tt = 0; tt <= s; ++tt) {
        float d = __expf(esm[tt] - pm);
        float c = (q0 * ksm[tt*4] + q1 * ksm[tt*4+1] + q2 * ksm[tt*4+2] + q3 * ksm[tt*4+3]) * d;
        csum += c;
        h0 += c * vsm[tt*4]; h1 += c * vsm[tt*4+1]; h2 += c * vsm[tt*4+2]; h3 += c * vsm[tt*4+3];
      }
      float norm = fmaxf(fabsf(csum), __expf(-mx)) + 1e-6f;
      float r = 1.0f / norm;
      h0 *= r; h1 *= r; h2 *= r; h3 *= r;
      float mu = (h0 + h1 + h2 + h3) * 0.25f;
      float d0 = h0 - mu, d1 = h1 - mu, d2 = h2 - mu, d3 = h3 - mu;
      float var = (d0 * d0 + d1 * d1 + d2 * d2 + d3 * d3) * 0.25f;
      float inv = rsqrtf(var + 1e-5f);
      *(float4*)&hbuf[s * INNER + n * 4] = make_float4(
          d0 * inv * onw[n * 4 + 0], d1 * inv * onw[n * 4 + 1],
          d2 * inv * onw[n * 4 + 2], d3 * inv * onw[n * 4 + 3]);
    }
  }
  gbar(cnt, gen);

  // ---------- P6: down-proj GEMM with fused h2 epilogue (216 blocks) ----------
  if (bid < 216) {
    int m0 = (bid % 36) * 16, n0 = (bid / 36) * 32;
    float* As = lds;               // [384][20]
    float* Bs = lds + INNER * DNA; // [384][36]
    for (int idx = t; idx < 16 * 96; idx += BLK) {
      int r = idx / 96, k4 = idx % 96;
      int s = m0 + r;
      float4 zv = *(const float4*)&xinner[s * (2 * INNER) + INNER + 4 * k4];
      float4 hm = *(const float4*)&hbuf[s * INNER + 4 * k4];
      float4 xv = *(const float4*)&xa[s * INNER + 4 * k4];
      float4 sk = *(const float4*)&skip[4 * k4];
      float z, sil;
      z = zv.x; sil = z / (1.0f + __expf(-z));
      As[(4 * k4 + 0) * DNA + r] = (hm.x + sk.x * xv.x) * sil;
      z = zv.y; sil = z / (1.0f + __expf(-z));
      As[(4 * k4 + 1) * DNA + r] = (hm.y + sk.y * xv.y) * sil;
      z = zv.z; sil = z / (1.0f + __expf(-z));
      As[(4 * k4 + 2) * DNA + r] = (hm.z + sk.z * xv.z) * sil;
      z = zv.w; sil = z / (1.0f + __expf(-z));
      As[(4 * k4 + 3) * DNA + r] = (hm.w + sk.w * xv.w) * sil;
    }
    for (int idx = t; idx < 32 * 96; idx += BLK) {
      int r = idx / 96, k4 = idx % 96;
      float4 v = *(const float4*)&dw[(n0 + r) * INNER + 4 * k4];
      Bs[(4 * k4 + 0) * DNB + r] = v.x;
      Bs[(4 * k4 + 1) * DNB + r] = v.y;
      Bs[(4 * k4 + 2) * DNB + r] = v.z;
      Bs[(4 * k4 + 3) * DNB + r] = v.w;
    }
    __syncthreads();
    if (t < 128) {
      int gm = t >> 4, gn = t & 15;
      float acc[2][2];
      #pragma unroll
      for (int i = 0; i < 2; ++i)
        #pragma unroll
        for (int j = 0; j < 2; ++j) acc[i][j] = db[n0 + 2 * gn + j];
      #pragma unroll 4
      for (int kk = 0; kk < INNER; ++kk) {
        float2 a = *(const float2*)&As[kk * DNA + 2 * gm];
        float2 bv = *(const float2*)&Bs[kk * DNB + 2 * gn];
        acc[0][0] += a.x * bv.x; acc[0][1] += a.x * bv.y;
        acc[1][0] += a.y * bv.x; acc[1][1] += a.y * bv.y;
      }
      #pragma unroll
      for (int i = 0; i < 2; ++i)
        *(float2*)&out[(m0 + 2 * gm + i) * DIM + n0 + 2 * gn] =
            make_float2(acc[i][0], acc[i][1]);
    }
  }
}

extern "C" void kernel_launch(void* const* d_in, const int* in_sizes, int n_in,
                              void* d_out, int out_size, void* d_ws, size_t ws_size,
                              hipStream_t stream) {
  const float* x      = (const float*)d_in[0];
  const float* ln_w   = (const float*)d_in[2];
  const float* ln_b   = (const float*)d_in[3];
  const float* up_w   = (const float*)d_in[4];
  const float* up_b   = (const float*)d_in[5];
  const float* q_w    = (const float*)d_in[8];
  const float* q_b    = (const float*)d_in[9];
  const float* k_w    = (const float*)d_in[10];
  const float* k_b    = (const float*)d_in[11];
  const float* v_w    = (const float*)d_in[12];
  const float* v_b    = (const float*)d_in[13];
  const float* conv_w = (const float*)d_in[14];
  const float* conv_b = (const float*)d_in[15];
  const float* ig_w   = (const float*)d_in[16];
  const float* ig_b   = (const float*)d_in[17];
  const float* fg_w   = (const float*)d_in[18];
  const float* fg_b   = (const float*)d_in[19];
  const float* onorm_w= (const float*)d_in[20];
  const float* skip   = (const float*)d_in[21];
  const float* down_w = (const float*)d_in[22];
  const float* down_b = (const float*)d_in[23];
  float* out = (float*)d_out;

  unsigned* bar = (unsigned*)d_ws;          // 64 floats reserved
  float* ws     = (float*)d_ws + 64;
  float* xinner = ws;                       // 576*768
  float* xa     = xinner + SEQ * 2 * INNER; // 576*384
  float* ginT   = xa + SEQ * INNER;         // 1152*576
  float* pig    = ginT + GIN * SEQ;         // 4*96*576
  float* pfg    = pig + GKS * NHEAD * SEQ;  // 4*96*576
  float* es_g   = pfg + GKS * NHEAD * SEQ;  // 96*576
  float* pm_g   = es_g + NHEAD * SEQ;       // 96*576
  float* mx_g   = pm_g + NHEAD * SEQ;       // 96*576
  float* hbuf   = mx_g + NHEAD * SEQ;       // 576*384

  hipMemsetAsync(d_ws, 0, 256, stream);
  k_mega<<<dim3(NB), dim3(BLK), 0, stream>>>(
      x, ln_w, ln_b, up_w, up_b, q_w, q_b, k_w, k_b, v_w, v_b,
      conv_w, conv_b, ig_w, ig_b, fg_w, fg_b, onorm_w, skip,
      down_w, down_b, out,
      xinner, xa, ginT, pig, pfg, es_g, pm_g, mx_g, hbuf, bar);
}

// Round 8
// 102.219 us; speedup vs baseline: 2.8890x; 2.8890x over previous
//
#include <hip/hip_runtime.h>
#include <math.h>

#define SEQ 576
#define DIM 192
#define INNER 384
#define NHEAD 96
#define HS 24
#define WSZ 24
#define GIN 1152
#define GKS 4

// 1) fused LayerNorm + up-proj GEMM: x_inner = LN(x) @ up_w.T + up_b
//    grid (9,24): BM=64 x BN=32, 256 thr. LN done in LDS (coalesced).
#define UPA 68
#define UPB 36
__global__ __launch_bounds__(256) void k_up(const float* __restrict__ x,
    const float* __restrict__ lnw, const float* __restrict__ lnb,
    const float* __restrict__ w, const float* __restrict__ b,
    float* __restrict__ out) {
  int m0 = blockIdx.x * 64, n0 = blockIdx.y * 32;
  __shared__ float As[DIM * UPA];   // [k][m]
  __shared__ float Bs[DIM * UPB];   // [k][o]
  __shared__ float mu[64], inv[64], ps[192];
  int t = threadIdx.x;
  for (int idx = t; idx < 64 * 48; idx += 256) {
    int r = idx / 48, k4 = idx % 48;
    float4 v = *(const float4*)&x[(m0 + r) * DIM + 4 * k4];
    As[(4 * k4 + 0) * UPA + r] = v.x;
    As[(4 * k4 + 1) * UPA + r] = v.y;
    As[(4 * k4 + 2) * UPA + r] = v.z;
    As[(4 * k4 + 3) * UPA + r] = v.w;
  }
  for (int idx = t; idx < 32 * 48; idx += 256) {
    int r = idx / 48, k4 = idx % 48;
    float4 v = *(const float4*)&w[(n0 + r) * DIM + 4 * k4];
    Bs[(4 * k4 + 0) * UPB + r] = v.x;
    Bs[(4 * k4 + 1) * UPB + r] = v.y;
    Bs[(4 * k4 + 2) * UPB + r] = v.z;
    Bs[(4 * k4 + 3) * UPB + r] = v.w;
  }
  __syncthreads();
  if (t < 192) {
    int r = t % 64, ph = t / 64;
    float s_ = 0.f;
    #pragma unroll 8
    for (int k = ph * 64; k < ph * 64 + 64; ++k) s_ += As[k * UPA + r];
    ps[t] = s_;
  }
  __syncthreads();
  if (t < 64) mu[t] = (ps[t] + ps[64 + t] + ps[128 + t]) * (1.0f / DIM);
  __syncthreads();
  if (t < 192) {
    int r = t % 64, ph = t / 64;
    float m_ = mu[r], s_ = 0.f;
    #pragma unroll 8
    for (int k = ph * 64; k < ph * 64 + 64; ++k) {
      float d = As[k * UPA + r] - m_; s_ += d * d;
    }
    ps[t] = s_;
  }
  __syncthreads();
  if (t < 64) inv[t] = rsqrtf((ps[t] + ps[64 + t] + ps[128 + t]) * (1.0f / DIM) + 1e-5f);
  __syncthreads();
  for (int idx = t; idx < 64 * DIM; idx += 256) {
    int k = idx / 64, r = idx % 64;
    As[k * UPA + r] = (As[k * UPA + r] - mu[r]) * inv[r] * lnw[k] + lnb[k];
  }
  __syncthreads();
  int gm = t >> 4, gn = t & 15;
  float acc[4][2];
  #pragma unroll
  for (int i = 0; i < 4; ++i)
    #pragma unroll
    for (int j = 0; j < 2; ++j) acc[i][j] = b[n0 + 2 * gn + j];
  #pragma unroll 4
  for (int kk = 0; kk < DIM; ++kk) {
    float4 a = *(const float4*)&As[kk * UPA + 4 * gm];
    float2 bv = *(const float2*)&Bs[kk * UPB + 2 * gn];
    acc[0][0] += a.x * bv.x; acc[0][1] += a.x * bv.y;
    acc[1][0] += a.y * bv.x; acc[1][1] += a.y * bv.y;
    acc[2][0] += a.z * bv.x; acc[2][1] += a.z * bv.y;
    acc[3][0] += a.w * bv.x; acc[3][1] += a.w * bv.y;
  }
  #pragma unroll
  for (int i = 0; i < 4; ++i)
    *(float2*)&out[(m0 + 4 * gm + i) * (2 * INNER) + n0 + 2 * gn] =
        make_float2(acc[i][0], acc[i][1]);
}

// 2) fused conv3x3+SiLU+qkv, block per token (576 x 384thr)
__global__ __launch_bounds__(384) void k_cqkv(const float* __restrict__ xin,
    const float* __restrict__ cw, const float* __restrict__ cb,
    const float* __restrict__ qw, const float* __restrict__ qb,
    const float* __restrict__ kw, const float* __restrict__ kb,
    const float* __restrict__ vw, const float* __restrict__ vb,
    float* __restrict__ xa, float* __restrict__ ginT) {
  int s = blockIdx.x, t = threadIdx.x;
  int h = s / WSZ, wc = s % WSZ;
  __shared__ float xat[INNER], xmt[INNER];
  float acc = cb[t];
  #pragma unroll
  for (int kh = 0; kh < 3; ++kh) {
    int hh = h + kh - 1;
    if (hh < 0 || hh >= HS) continue;
    #pragma unroll
    for (int kw2 = 0; kw2 < 3; ++kw2) {
      int ww = wc + kw2 - 1;
      if (ww < 0 || ww >= WSZ) continue;
      acc += xin[(hh * WSZ + ww) * (2 * INNER) + t] * cw[t * 9 + kh * 3 + kw2];
    }
  }
  float sil = acc / (1.0f + __expf(-acc));
  xat[t] = sil;
  xa[s * INNER + t] = sil;
  xmt[t] = xin[s * (2 * INNER) + t];
  __syncthreads();
  int n = t >> 2, o = t & 3;
  const float* xah = xat + n * 4;
  const float* xmh = xmt + n * 4;
  float q = qb[t], k = kb[t], v = vb[t];
  #pragma unroll
  for (int i = 0; i < 4; ++i) {
    float xq = xah[i], xm = xmh[i];
    q += xq * qw[n * 16 + o * 4 + i];
    k += xq * kw[n * 16 + o * 4 + i];
    v += xm * vw[n * 16 + o * 4 + i];
  }
  ginT[t * SEQ + s]               = q;
  ginT[(INNER + t) * SEQ + s]     = k;
  ginT[(2 * INNER + t) * SEQ + s] = v;
}

// 3) gate GEMM: C[192,576] = W[192,1152] @ ginT, K-split 4, single-shot stage.
#define GBK 288
#define WP 36
__global__ __launch_bounds__(256) void k_gates(const float* __restrict__ ginT,
    const float* __restrict__ igw, const float* __restrict__ fgw,
    float* __restrict__ pig, float* __restrict__ pfg) {
  int bx = blockIdx.x, s0 = blockIdx.y * 64, ks = blockIdx.z;
  int k0 = ks * GBK;
  bool isig = bx < 3;
  int m0 = (isig ? bx : bx - 3) * 32;
  const float* wb = (isig ? igw : fgw) + m0 * GIN;
  __shared__ float Ws[GBK * WP];
  __shared__ float Gs[GBK * 64];
  int t = threadIdx.x;
  for (int idx = t; idx < 32 * 72; idx += 256) {
    int r = idx / 72, k4 = idx % 72;
    float4 v = *(const float4*)&wb[r * GIN + k0 + 4 * k4];
    Ws[(4 * k4 + 0) * WP + r] = v.x;
    Ws[(4 * k4 + 1) * WP + r] = v.y;
    Ws[(4 * k4 + 2) * WP + r] = v.z;
    Ws[(4 * k4 + 3) * WP + r] = v.w;
  }
  for (int idx = t; idx < GBK * 16; idx += 256) {
    int kk = idx / 16, s4 = idx % 16;
    *(float4*)&Gs[kk * 64 + 4 * s4] =
        *(const float4*)&ginT[(k0 + kk) * SEQ + s0 + 4 * s4];
  }
  __syncthreads();
  int gm = t >> 4, gn = t & 15;
  float acc[2][4] = {{0.f,0.f,0.f,0.f},{0.f,0.f,0.f,0.f}};
  #pragma unroll 4
  for (int kk = 0; kk < GBK; ++kk) {
    float2 wv = *(const float2*)&Ws[kk * WP + 2 * gm];
    float4 gv = *(const float4*)&Gs[kk * 64 + 4 * gn];
    acc[0][0] += wv.x * gv.x; acc[0][1] += wv.x * gv.y;
    acc[0][2] += wv.x * gv.z; acc[0][3] += wv.x * gv.w;
    acc[1][0] += wv.y * gv.x; acc[1][1] += wv.y * gv.y;
    acc[1][2] += wv.y * gv.z; acc[1][3] += wv.y * gv.w;
  }
  float* dstp = (isig ? pig : pfg) + ks * NHEAD * SEQ;
  #pragma unroll
  for (int i = 0; i < 2; ++i) {
    int mm = m0 + 2 * gm + i;
    *(float4*)&dstp[mm * SEQ + s0 + 4 * gn] =
        make_float4(acc[i][0], acc[i][1], acc[i][2], acc[i][3]);
  }
}

// 4) mLSTM: combine partials + log-sigmoid + block scans (sum & max) +
//    triangular accumulate (2 threads/row) + groupnorm.
//    grid (96 heads, 2 seq-halves), 576 threads.
__global__ __launch_bounds__(576) void k_mlstm(const float* __restrict__ ginT,
    const float* __restrict__ pig, const float* __restrict__ pfg,
    const float* __restrict__ igb, const float* __restrict__ fgb,
    const float* __restrict__ onw, float* __restrict__ hout) {
  int n = blockIdx.x, hh = blockIdx.y, t = threadIdx.x;
  int cnt2 = 288 * (hh + 1);
  __shared__ float ksm[SEQ * 4], vsm[SEQ * 4], esm[SEQ];
  __shared__ float bufA[SEQ], bufB[SEQ], bufC[SEQ];
  const int H4 = NHEAD * SEQ;
  float ai = 0.f;
  if (t < cnt2) {
    // stage k (scaled), v
    float a0 = ginT[(INNER + n * 4 + 0) * SEQ + t] * 0.5f;
    float a1 = ginT[(INNER + n * 4 + 1) * SEQ + t] * 0.5f;
    float a2 = ginT[(INNER + n * 4 + 2) * SEQ + t] * 0.5f;
    float a3 = ginT[(INNER + n * 4 + 3) * SEQ + t] * 0.5f;
    *(float4*)&ksm[t * 4] = make_float4(a0, a1, a2, a3);
    float b0 = ginT[(2 * INNER + n * 4 + 0) * SEQ + t];
    float b1 = ginT[(2 * INNER + n * 4 + 1) * SEQ + t];
    float b2 = ginT[(2 * INNER + n * 4 + 2) * SEQ + t];
    float b3 = ginT[(2 * INNER + n * 4 + 3) * SEQ + t];
    *(float4*)&vsm[t * 4] = make_float4(b0, b1, b2, b3);
    int off = n * SEQ + t;
    ai = igb[n] + pig[off] + pig[off + H4] + pig[off + 2 * H4] + pig[off + 3 * H4];
    float af = fgb[n] + pfg[off] + pfg[off + H4] + pfg[off + 2 * H4] + pfg[off + 3 * H4];
    float lf = (af >= 0.f) ? -log1pf(expf(-af)) : (af - log1pf(expf(af)));
    bufA[t] = lf;
  }
  __syncthreads();
  // block-wide inclusive sum scan over [0, cnt2)
  float* src = bufA; float* dst = bufB;
  for (int o2 = 1; o2 < cnt2; o2 <<= 1) {
    if (t < cnt2) {
      float v = src[t];
      if (t >= o2) v += src[t - o2];
      dst[t] = v;
    }
    __syncthreads();
    float* tmp = src; src = dst; dst = tmp;
  }
  // src = lfc array; compute es into esm and seed max scan in dst
  if (t < cnt2) {
    float e = ai - src[t];
    esm[t] = e;
    dst[t] = e;
  }
  __syncthreads();
  float* srcM = dst; float* dstM = bufC;
  for (int o2 = 1; o2 < cnt2; o2 <<= 1) {
    if (t < cnt2) {
      float v = srcM[t];
      if (t >= o2) v = fmaxf(v, srcM[t - o2]);
      dstM[t] = v;
    }
    __syncthreads();
    float* tmp = srcM; srcM = dstM; dstM = tmp;
  }
  // srcM = prefix-max array, src = lfc array
  int r = (t < 288) ? t : t - 288;
  int half = (t >= 288) ? 1 : 0;
  int s = 288 * hh + r;
  float pm = srcM[s];
  float mxv = src[s] + pm;
  float q0 = ginT[(n * 4 + 0) * SEQ + s];
  float q1 = ginT[(n * 4 + 1) * SEQ + s];
  float q2 = ginT[(n * 4 + 2) * SEQ + s];
  float q3 = ginT[(n * 4 + 3) * SEQ + s];
  int N = s + 1, nA = (N + 1) >> 1;
  int lo = half ? nA : 0, hi = half ? N : nA;
  float csum = 0.f, h0 = 0.f, h1 = 0.f, h2 = 0.f, h3 = 0.f;
  for (int tt = lo; tt < hi; ++tt) {
    float d = __expf(esm[tt] - pm);
    float c = (q0 * ksm[tt*4] + q1 * ksm[tt*4+1] + q2 * ksm[tt*4+2] + q3 * ksm[tt*4+3]) * d;
    csum += c;
    h0 += c * vsm[tt*4]; h1 += c * vsm[tt*4+1]; h2 += c * vsm[tt*4+2]; h3 += c * vsm[tt*4+3];
  }
  __syncthreads();            // all reads of ksm done; reuse it for partials
  if (half) {
    ksm[r * 5 + 0] = csum; ksm[r * 5 + 1] = h0; ksm[r * 5 + 2] = h1;
    ksm[r * 5 + 3] = h2;   ksm[r * 5 + 4] = h3;
  }
  __syncthreads();
  if (!half) {
    csum += ksm[r * 5 + 0];
    h0 += ksm[r * 5 + 1]; h1 += ksm[r * 5 + 2];
    h2 += ksm[r * 5 + 3]; h3 += ksm[r * 5 + 4];
    float norm = fmaxf(fabsf(csum), __expf(-mxv)) + 1e-6f;
    float rr = 1.0f / norm;
    h0 *= rr; h1 *= rr; h2 *= rr; h3 *= rr;
    float mu = (h0 + h1 + h2 + h3) * 0.25f;
    float d0 = h0 - mu, d1 = h1 - mu, d2 = h2 - mu, d3 = h3 - mu;
    float var = (d0 * d0 + d1 * d1 + d2 * d2 + d3 * d3) * 0.25f;
    float inv = rsqrtf(var + 1e-5f);
    *(float4*)&hout[s * INNER + n * 4] = make_float4(
        d0 * inv * onw[n * 4 + 0], d1 * inv * onw[n * 4 + 1],
        d2 * inv * onw[n * 4 + 2], d3 * inv * onw[n * 4 + 3]);
  }
}

// 5) tiled GEMM, fused h2 epilogue-A: out = h2 @ down_w.T + down_b
#define DNA 20
#define DNB 36
__global__ __launch_bounds__(128) void k_down(const float* __restrict__ hmat,
    const float* __restrict__ xa, const float* __restrict__ xin,
    const float* __restrict__ skip, const float* __restrict__ dw,
    const float* __restrict__ db, float* __restrict__ out) {
  int m0 = blockIdx.x * 16, n0 = blockIdx.y * 32;
  __shared__ float As[INNER * DNA];
  __shared__ float Bs[INNER * DNB];
  int t = threadIdx.x;
  for (int idx = t; idx < 16 * 96; idx += 128) {
    int r = idx / 96, k4 = idx % 96;
    int s = m0 + r;
    float4 zv = *(const float4*)&xin[s * (2 * INNER) + INNER + 4 * k4];
    float4 hm = *(const float4*)&hmat[s * INNER + 4 * k4];
    float4 xv = *(const float4*)&xa[s * INNER + 4 * k4];
    float4 sk = *(const float4*)&skip[4 * k4];
    float z, sil;
    z = zv.x; sil = z / (1.0f + __expf(-z));
    As[(4 * k4 + 0) * DNA + r] = (hm.x + sk.x * xv.x) * sil;
    z = zv.y; sil = z / (1.0f + __expf(-z));
    As[(4 * k4 + 1) * DNA + r] = (hm.y + sk.y * xv.y) * sil;
    z = zv.z; sil = z / (1.0f + __expf(-z));
    As[(4 * k4 + 2) * DNA + r] = (hm.z + sk.z * xv.z) * sil;
    z = zv.w; sil = z / (1.0f + __expf(-z));
    As[(4 * k4 + 3) * DNA + r] = (hm.w + sk.w * xv.w) * sil;
  }
  for (int idx = t; idx < 32 * 96; idx += 128) {
    int r = idx / 96, k4 = idx % 96;
    float4 v = *(const float4*)&dw[(n0 + r) * INNER + 4 * k4];
    Bs[(4 * k4 + 0) * DNB + r] = v.x;
    Bs[(4 * k4 + 1) * DNB + r] = v.y;
    Bs[(4 * k4 + 2) * DNB + r] = v.z;
    Bs[(4 * k4 + 3) * DNB + r] = v.w;
  }
  __syncthreads();
  int gm = t >> 4, gn = t & 15;
  float acc[2][2];
  #pragma unroll
  for (int i = 0; i < 2; ++i)
    #pragma unroll
    for (int j = 0; j < 2; ++j) acc[i][j] = db[n0 + 2 * gn + j];
  #pragma unroll 4
  for (int kk = 0; kk < INNER; ++kk) {
    float2 a = *(const float2*)&As[kk * DNA + 2 * gm];
    float2 bv = *(const float2*)&Bs[kk * DNB + 2 * gn];
    acc[0][0] += a.x * bv.x; acc[0][1] += a.x * bv.y;
    acc[1][0] += a.y * bv.x; acc[1][1] += a.y * bv.y;
  }
  #pragma unroll
  for (int i = 0; i < 2; ++i)
    *(float2*)&out[(m0 + 2 * gm + i) * DIM + n0 + 2 * gn] =
        make_float2(acc[i][0], acc[i][1]);
}

extern "C" void kernel_launch(void* const* d_in, const int* in_sizes, int n_in,
                              void* d_out, int out_size, void* d_ws, size_t ws_size,
                              hipStream_t stream) {
  const float* x      = (const float*)d_in[0];
  const float* ln_w   = (const float*)d_in[2];
  const float* ln_b   = (const float*)d_in[3];
  const float* up_w   = (const float*)d_in[4];
  const float* up_b   = (const float*)d_in[5];
  const float* q_w    = (const float*)d_in[8];
  const float* q_b    = (const float*)d_in[9];
  const float* k_w    = (const float*)d_in[10];
  const float* k_b    = (const float*)d_in[11];
  const float* v_w    = (const float*)d_in[12];
  const float* v_b    = (const float*)d_in[13];
  const float* conv_w = (const float*)d_in[14];
  const float* conv_b = (const float*)d_in[15];
  const float* ig_w   = (const float*)d_in[16];
  const float* ig_b   = (const float*)d_in[17];
  const float* fg_w   = (const float*)d_in[18];
  const float* fg_b   = (const float*)d_in[19];
  const float* onorm_w= (const float*)d_in[20];
  const float* skip   = (const float*)d_in[21];
  const float* down_w = (const float*)d_in[22];
  const float* down_b = (const float*)d_in[23];
  float* out = (float*)d_out;

  float* ws     = (float*)d_ws;
  float* xinner = ws;                       // 576*768
  float* xa     = xinner + SEQ * 2 * INNER; // 576*384
  float* ginT   = xa + SEQ * INNER;         // 1152*576
  float* pig    = ginT + GIN * SEQ;         // 4*96*576
  float* pfg    = pig + GKS * NHEAD * SEQ;  // 4*96*576
  float* hbuf   = pfg + GKS * NHEAD * SEQ;  // 576*384

  k_up   <<<dim3(9, 24), 256, 0, stream>>>(x, ln_w, ln_b, up_w, up_b, xinner);
  k_cqkv <<<SEQ, 384, 0, stream>>>(xinner, conv_w, conv_b,
                                   q_w, q_b, k_w, k_b, v_w, v_b, xa, ginT);
  k_gates<<<dim3(6, 9, GKS), 256, 0, stream>>>(ginT, ig_w, fg_w, pig, pfg);
  k_mlstm<<<dim3(NHEAD, 2), 576, 0, stream>>>(ginT, pig, pfg, ig_b, fg_b, onorm_w, hbuf);
  k_down <<<dim3(36, 6), 128, 0, stream>>>(hbuf, xa, xinner, skip, down_w, down_b, out);
}